// Round 6
// baseline (660.122 us; speedup 1.0000x reference)
//
#include <hip/hip_runtime.h>

#define N_NODES 200000
#define N_EDGES 1200000
#define F_IN    64
#define F_H     128
#define BN_EPS  1e-5f

typedef short bf16x8 __attribute__((ext_vector_type(8)));   // 8 bf16 in 4 VGPRs
typedef float f32x4  __attribute__((ext_vector_type(4)));
typedef unsigned short us4 __attribute__((ext_vector_type(4)));

__device__ __forceinline__ unsigned short f2bf(float f) {
    union { float f; unsigned u; } v; v.f = f;
    unsigned r = (v.u + 0x7FFFu + ((v.u >> 16) & 1u)) >> 16;  // RNE
    return (unsigned short)r;
}
__device__ __forceinline__ float bf2f(unsigned short b) {
    union { unsigned u; float f; } v; v.u = ((unsigned)b) << 16;
    return v.f;
}

// ---------------------------------------------------------------------------
// Weight pack into bf16 MFMA B-fragment order for mfma_f32_16x16x32_bf16:
// element j of lane L in (nt,kt) tile = W[kt*32+(L>>4)*8+j][nt*16+(L&15)],
// optionally pre-scaled per-k (folds BN1 scale into layer-2 weights).
// ---------------------------------------------------------------------------
__global__ void pack_weights_kernel(const float* __restrict__ W,
                                    const float* __restrict__ kscale,
                                    short* __restrict__ P, int KT)
{
    int t = blockIdx.x * 256 + threadIdx.x;            // over 8*KT*64
    if (t >= 8 * KT * 64) return;
    int lane = t & 63;
    int kt   = (t >> 6) % KT;
    int nt   = t / (64 * KT);
    int k0   = kt * 32 + (lane >> 4) * 8;
    int n    = nt * 16 + (lane & 15);
#pragma unroll
    for (int j = 0; j < 8; ++j) {
        float w = W[(size_t)(k0 + j) * 128 + n];
        if (kscale) w *= kscale[k0 + j];
        P[(size_t)t * 8 + j] = (short)f2bf(w);
    }
}

// ---------------------------------------------------------------------------
// CSR build: histogram -> 2-level exclusive scan -> cursor fill
// ---------------------------------------------------------------------------
__global__ __launch_bounds__(256) void hist_kernel(const int* __restrict__ ei,
                                                   int* __restrict__ deg, int E)
{
    int e = blockIdx.x * 256 + threadIdx.x;
    if (e < E) atomicAdd(&deg[ei[E + e]], 1);
}

__global__ __launch_bounds__(256) void scan1_kernel(const int* __restrict__ deg,
        int* __restrict__ part, int* __restrict__ bsum, int n)
{
    __shared__ int s[256];
    int t = threadIdx.x;
    int base = blockIdx.x * 1024 + t * 4;
    int v[4];
#pragma unroll
    for (int j = 0; j < 4; ++j) v[j] = (base + j < n) ? deg[base + j] : 0;
    int tsum = v[0] + v[1] + v[2] + v[3];
    s[t] = tsum;
    __syncthreads();
    for (int off = 1; off < 256; off <<= 1) {
        int xv = (t >= off) ? s[t - off] : 0;
        __syncthreads();
        s[t] += xv;
        __syncthreads();
    }
    int excl = s[t] - tsum;
#pragma unroll
    for (int j = 0; j < 4; ++j) {
        if (base + j < n) part[base + j] = excl;
        excl += v[j];
    }
    if (t == 255) bsum[blockIdx.x] = s[255];
}

__global__ void scan2_kernel(int* __restrict__ bsum, int nb)
{
    __shared__ int s[256];
    int t = threadIdx.x;
    int v = (t < nb) ? bsum[t] : 0;
    s[t] = v;
    __syncthreads();
    for (int off = 1; off < 256; off <<= 1) {
        int xv = (t >= off) ? s[t - off] : 0;
        __syncthreads();
        s[t] += xv;
        __syncthreads();
    }
    if (t < nb) bsum[t] = s[t] - v;   // exclusive
}

__global__ __launch_bounds__(256) void scan3_kernel(
    const int* __restrict__ part, const int* __restrict__ bsum,
    const int* __restrict__ deg, int* __restrict__ rowptr,
    int* __restrict__ cursor, float* __restrict__ degf, int n, int E)
{
    int i = blockIdx.x * 256 + threadIdx.x;
    if (i == 0) rowptr[n] = E;
    if (i >= n) return;
    int r = part[i] + bsum[i >> 10];
    rowptr[i] = r;
    cursor[i] = r;
    degf[i]   = (float)deg[i];
}

__global__ __launch_bounds__(256) void fill_kernel(const int* __restrict__ ei,
        int* __restrict__ cursor, int* __restrict__ ssrc, int E)
{
    int e = blockIdx.x * 256 + threadIdx.x;
    if (e >= E) return;
    int d = ei[E + e];
    int pos = atomicAdd(&cursor[d], 1);
    ssrc[pos] = ei[e];
}

// ---------------------------------------------------------------------------
// Gather-aggregate layer 1: aggb[row,0:64] = bf16( sum_src x[src,:] ).
// 4 rows per wave + software-pipelined ssrc prefetch.
// ---------------------------------------------------------------------------
__global__ __launch_bounds__(256) void gather1_kernel(
    const float* __restrict__ x, const int* __restrict__ rowptr,
    const int* __restrict__ ssrc, unsigned short* __restrict__ aggb)
{
    const int tid  = threadIdx.x;
    const int wv   = tid >> 6;
    const int lane = tid & 63;
    const int sub  = lane >> 4;
    const int li   = lane & 15;
    const int row  = blockIdx.x * 16 + wv * 4 + sub;

    int b = rowptr[row], e = rowptr[row + 1];
    float4 acc = {0.f, 0.f, 0.f, 0.f};
    if (b < e) {
        int s = ssrc[b];
        for (int j = b; j < e; ++j) {
            int sn = (j + 1 < e) ? ssrc[j + 1] : 0;   // prefetch next index
            float4 v = ((const float4*)(x + (size_t)s * F_IN))[li];
            acc.x += v.x; acc.y += v.y; acc.z += v.z; acc.w += v.w;
            s = sn;
        }
    }
    us4 o;
    o.x = f2bf(acc.x); o.y = f2bf(acc.y); o.z = f2bf(acc.z); o.w = f2bf(acc.w);
    *(us4*)(aggb + (size_t)row * F_IN + li * 4) = o;
}

// ---------------------------------------------------------------------------
// Gather-aggregate layer 2: aggb[row,0:128] = bf16( sum_src t1[src,:] ).
// ---------------------------------------------------------------------------
__global__ __launch_bounds__(256) void gather2_kernel(
    const unsigned short* __restrict__ t1, const int* __restrict__ rowptr,
    const int* __restrict__ ssrc, unsigned short* __restrict__ aggb)
{
    const int tid  = threadIdx.x;
    const int wv   = tid >> 6;
    const int lane = tid & 63;
    const int sub  = lane >> 4;
    const int li   = lane & 15;
    const int row  = blockIdx.x * 16 + wv * 4 + sub;

    int b = rowptr[row], e = rowptr[row + 1];
    float acc[8] = {};
    if (b < e) {
        int s = ssrc[b];
        for (int j = b; j < e; ++j) {
            int sn = (j + 1 < e) ? ssrc[j + 1] : 0;
            bf16x8 v = *(const bf16x8*)(t1 + (size_t)s * F_H + li * 8);
#pragma unroll
            for (int k = 0; k < 8; ++k) acc[k] += bf2f((unsigned short)v[k]);
            s = sn;
        }
    }
    bf16x8 o;
#pragma unroll
    for (int k = 0; k < 8; ++k) o[k] = (short)f2bf(acc[k]);
    *(bf16x8*)(aggb + (size_t)row * F_H + li * 8) = o;
}

// ---------------------------------------------------------------------------
// MFMA GEMM, flat-grid version: one 256-row tile per block, 4 waves x 64 rows
// (4 A-subtiles of 16). Weights read straight from global in fragment order
// (32-64 KB, L2-resident; no LDS staging -> occupancy is VGPR-limited, not
// LDS-limited; R5's 65 KB LDS collapsed occupancy to 8.7%).
// Per k-step per wave: 8 A/X loads + 16 weight b128 loads + 64 MFMA
// (4 independent subtile chains).
// Stats accumulate in registers -> LDS reduce -> 128 atomics per block into
// one of 4 gsum/gsq replicas (blockIdx&3) to cap per-address RMW chains.
// L1: out = relu(A@W1l + b1 + X@W1r), X fp32 -> t1 bf16.
// L2: out = relu(A@W2l' + Xb@W2r' + crb + deg*c2), Xb bf16, out fp32.
// ---------------------------------------------------------------------------
template<int K, bool L2>
__global__ __launch_bounds__(256) void gemm_mfma_kernel(
    const unsigned short* __restrict__ Ab,
    const float* __restrict__ Xf,
    const unsigned short* __restrict__ Xb,
    const bf16x8* __restrict__ Wlp, const bf16x8* __restrict__ Wrp,
    const float* __restrict__ bias,
    const float* __restrict__ c2, const float* __restrict__ degf,
    float* __restrict__ outF, unsigned short* __restrict__ outB,
    float* __restrict__ gsum, float* __restrict__ gsq)
{
    constexpr int KT = K / 32;
    __shared__ float sS[128];
    __shared__ float sQ[128];

    const int tid  = threadIdx.x;
    const int lane = tid & 63;
    const int wv   = tid >> 6;
    const int m    = lane & 15;
    const int quad = lane >> 4;
    const int rowbase = blockIdx.x * 256 + wv * 64;

    if (tid < 128) { sS[tid] = 0.f; sQ[tid] = 0.f; }

    // per-nt epilogue constants (col = nt*16 + m)
    float bcol[8], ccol[8];
#pragma unroll
    for (int nt = 0; nt < 8; ++nt) {
        bcol[nt] = bias[nt * 16 + m];
        if constexpr (L2) ccol[nt] = c2[nt * 16 + m];
    }

    f32x4 acc[4][8] = {};

#pragma unroll
    for (int kt = 0; kt < KT; ++kt) {
        const int k0 = kt * 32 + quad * 8;
        bf16x8 af[4], xf[4];
#pragma unroll
        for (int st = 0; st < 4; ++st) {
            int r  = rowbase + st * 16 + m;
            int rc = r < N_NODES ? r : N_NODES - 1;
            af[st] = *(const bf16x8*)(Ab + (size_t)rc * K + k0);
            if constexpr (L2) {
                xf[st] = *(const bf16x8*)(Xb + (size_t)rc * K + k0);
            } else {
                const float4* xp = (const float4*)(Xf + (size_t)rc * K + k0);
                float4 x0 = xp[0], x1 = xp[1];
                xf[st][0] = (short)f2bf(x0.x); xf[st][1] = (short)f2bf(x0.y);
                xf[st][2] = (short)f2bf(x0.z); xf[st][3] = (short)f2bf(x0.w);
                xf[st][4] = (short)f2bf(x1.x); xf[st][5] = (short)f2bf(x1.y);
                xf[st][6] = (short)f2bf(x1.z); xf[st][7] = (short)f2bf(x1.w);
            }
        }
#pragma unroll
        for (int nt = 0; nt < 8; ++nt) {
            bf16x8 wl = Wlp[(nt * KT + kt) * 64 + lane];
#pragma unroll
            for (int st = 0; st < 4; ++st)
                acc[st][nt] = __builtin_amdgcn_mfma_f32_16x16x32_bf16(
                    af[st], wl, acc[st][nt], 0, 0, 0);
            bf16x8 wr = Wrp[(nt * KT + kt) * 64 + lane];
#pragma unroll
            for (int st = 0; st < 4; ++st)
                acc[st][nt] = __builtin_amdgcn_mfma_f32_16x16x32_bf16(
                    xf[st], wr, acc[st][nt], 0, 0, 0);
        }
    }

    __syncthreads();   // sS/sQ init done

    // ---- epilogue: C/D layout col = lane&15, row = quad*4 + reg ----
    float stS[8] = {}, stQ[8] = {};
#pragma unroll
    for (int st = 0; st < 4; ++st) {
        const int orow = rowbase + st * 16 + quad * 4;
        float dg[4];
        if constexpr (L2) {
#pragma unroll
            for (int r = 0; r < 4; ++r) {
                int rr = orow + r;
                dg[r] = (rr < N_NODES) ? degf[rr] : 0.f;
            }
        }
#pragma unroll
        for (int nt = 0; nt < 8; ++nt) {
            int col = nt * 16 + m;
#pragma unroll
            for (int r = 0; r < 4; ++r) {
                int rr = orow + r;
                if (rr < N_NODES) {
                    float base = L2 ? fmaf(dg[r], ccol[nt], bcol[nt]) : bcol[nt];
                    float v = fmaxf(acc[st][nt][r] + base, 0.f);
                    if constexpr (L2) outF[(size_t)rr * 128 + col] = v;
                    else              outB[(size_t)rr * 128 + col] = f2bf(v);
                    stS[nt] += v;
                    stQ[nt] = fmaf(v, v, stQ[nt]);
                }
            }
        }
    }

    // ---- stats reduce: registers -> LDS -> global replica (blockIdx&3) ----
#pragma unroll
    for (int nt = 0; nt < 8; ++nt) {
        atomicAdd(&sS[nt * 16 + m], stS[nt]);
        atomicAdd(&sQ[nt * 16 + m], stQ[nt]);
    }
    __syncthreads();
    const int rep = (blockIdx.x & 3) * 128;
    if (tid < 128) {
        atomicAdd(&gsum[rep + tid], sS[tid]);
        atomicAdd(&gsq[rep + tid],  sQ[tid]);
    }
}

// ---------------------------------------------------------------------------
// BN finalize: per-feature scale/shift (sums the 4 stats replicas).
// ---------------------------------------------------------------------------
__global__ void bn_finalize_kernel(
    const float* __restrict__ gsum, const float* __restrict__ gsq,
    const float* __restrict__ g, const float* __restrict__ be,
    float* __restrict__ scale, float* __restrict__ shift, float invN)
{
    int c = threadIdx.x;  // 128
    float s = gsum[c] + gsum[128 + c] + gsum[256 + c] + gsum[384 + c];
    float q = gsq[c]  + gsq[128 + c]  + gsq[256 + c]  + gsq[384 + c];
    float mean = s * invN;
    float var  = fmaxf(q * invN - mean * mean, 0.f);
    float sc   = g[c] * rsqrtf(var + BN_EPS);
    scale[c] = sc;
    shift[c] = be[c] - mean * sc;
}

// BN1 fold constants: c2 = shift1@W2l ; crb = shift1@W2r + b2
__global__ void bn_fold_kernel(
    const float* __restrict__ shift1, const float* __restrict__ W2l,
    const float* __restrict__ W2r, const float* __restrict__ b2,
    float* __restrict__ c2, float* __restrict__ crb)
{
    int col = threadIdx.x;  // 128
    float a = 0.f, r = 0.f;
    for (int k = 0; k < 128; ++k) {
        float s = shift1[k];
        a = fmaf(s, W2l[(size_t)k * 128 + col], a);
        r = fmaf(s, W2r[(size_t)k * 128 + col], r);
    }
    c2[col]  = a;
    crb[col] = r + b2[col];
}

// ---------------------------------------------------------------------------
// Final BN apply + ReLU (in place on d_out).
// ---------------------------------------------------------------------------
__global__ __launch_bounds__(256) void bn_apply_relu_kernel(
    float* __restrict__ h, const float* __restrict__ scale,
    const float* __restrict__ shift, int n4)
{
    int i = blockIdx.x * 256 + threadIdx.x;
    if (i >= n4) return;
    int cb = i & 31;
    float4 v  = ((float4*)h)[i];
    float4 sc = ((const float4*)scale)[cb];
    float4 sh = ((const float4*)shift)[cb];
    v.x = fmaxf(fmaf(v.x, sc.x, sh.x), 0.f);
    v.y = fmaxf(fmaf(v.y, sc.y, sh.y), 0.f);
    v.z = fmaxf(fmaf(v.z, sc.z, sh.z), 0.f);
    v.w = fmaxf(fmaf(v.w, sc.w, sh.w), 0.f);
    ((float4*)h)[i] = v;
}

extern "C" void kernel_launch(void* const* d_in, const int* in_sizes, int n_in,
                              void* d_out, int out_size, void* d_ws, size_t ws_size,
                              hipStream_t stream) {
    const float* x   = (const float*)d_in[0];
    const int*   ei  = (const int*)d_in[1];
    const float* W1l = (const float*)d_in[2];
    const float* b1  = (const float*)d_in[3];
    const float* W1r = (const float*)d_in[4];
    const float* g1  = (const float*)d_in[5];
    const float* be1 = (const float*)d_in[6];
    const float* W2l = (const float*)d_in[7];
    const float* b2  = (const float*)d_in[8];
    const float* W2r = (const float*)d_in[9];
    const float* g2  = (const float*)d_in[10];
    const float* be2 = (const float*)d_in[11];
    float* out = (float*)d_out;

    const int N = N_NODES, E = N_EDGES;
    const int NB1 = (N + 1023) / 1024;          // 196 scan blocks
    const int nT  = (N + 255) / 256;            // 782 row-tile blocks

    // Workspace layout (float units):
    float* ws     = (float*)d_ws;
    float* gsum1  = ws;          float* gsq1   = ws + 512;    // 4 replicas x 128
    float* gsum2  = ws + 1024;   float* gsq2   = ws + 1536;
    float* scale1 = ws + 2048;   float* shift1 = ws + 2176;
    float* scale2 = ws + 2304;   float* shift2 = ws + 2432;
    float* c2v    = ws + 2560;   float* crb    = ws + 2688;
    short* W1lp = (short*)(ws + 3072);                        // 4096 f
    short* W1rp = (short*)(ws + 3072 + 4096);                 // 4096 f
    short* W2lp = (short*)(ws + 3072 + 8192);                 // 8192 f
    short* W2rp = (short*)(ws + 3072 + 16384);                // 8192 f
    int*   deg    = (int*)(ws + 27648);                       // N
    int*   part   = deg + N;                                  // N
    int*   bsum   = part + N;                                 // 1024
    int*   rowptr = bsum + 1024;                              // N+1
    int*   cursor = rowptr + (N + 1024);                      // N (padded)
    float* degf   = (float*)(cursor + N);                     // N
    int*   ssrc   = (int*)(degf + N);                         // E
    unsigned short* t1   = (unsigned short*)(ssrc + E);       // N*128 bf16
    unsigned short* aggb = t1 + (size_t)N * F_H;              // N*128 bf16

    // ---- Graph build + layer-1 weight pack ----
    hipMemsetAsync(ws, 0, 2048 * sizeof(float), stream);      // stats replicas
    hipMemsetAsync(deg, 0, (size_t)N * sizeof(int), stream);
    pack_weights_kernel<<<4, 256, 0, stream>>>(W1l, nullptr, W1lp, 2);
    pack_weights_kernel<<<4, 256, 0, stream>>>(W1r, nullptr, W1rp, 2);
    hist_kernel<<<(E + 255) / 256, 256, 0, stream>>>(ei, deg, E);
    scan1_kernel<<<NB1, 256, 0, stream>>>(deg, part, bsum, N);
    scan2_kernel<<<1, 256, 0, stream>>>(bsum, NB1);
    scan3_kernel<<<(N + 255) / 256, 256, 0, stream>>>(part, bsum, deg, rowptr,
                                                      cursor, degf, N, E);
    fill_kernel<<<(E + 255) / 256, 256, 0, stream>>>(ei, cursor, ssrc, E);

    // ---- Layer 1 ----
    gather1_kernel<<<N / 16, 256, 0, stream>>>(x, rowptr, ssrc, aggb);
    gemm_mfma_kernel<F_IN, false><<<nT, 256, 0, stream>>>(
        aggb, x, nullptr, (const bf16x8*)W1lp, (const bf16x8*)W1rp, b1,
        nullptr, nullptr, nullptr, t1, gsum1, gsq1);
    bn_finalize_kernel<<<1, 128, 0, stream>>>(gsum1, gsq1, g1, be1,
                                              scale1, shift1, 1.f / N);

    // ---- Layer 2 (BN1 folded: scale1 into weights, shift1 into c2/crb) ----
    pack_weights_kernel<<<8, 256, 0, stream>>>(W2l, scale1, W2lp, 4);
    pack_weights_kernel<<<8, 256, 0, stream>>>(W2r, scale1, W2rp, 4);
    bn_fold_kernel<<<1, 128, 0, stream>>>(shift1, W2l, W2r, b2, c2v, crb);
    gather2_kernel<<<N / 16, 256, 0, stream>>>(t1, rowptr, ssrc, aggb);
    gemm_mfma_kernel<F_H, true><<<nT, 256, 0, stream>>>(
        aggb, nullptr, t1, (const bf16x8*)W2lp, (const bf16x8*)W2rp, crb,
        c2v, degf, out, nullptr, gsum2, gsq2);
    bn_finalize_kernel<<<1, 128, 0, stream>>>(gsum2, gsq2, g2, be2,
                                              scale2, shift2, 1.f / N);
    bn_apply_relu_kernel<<<(N * F_H / 4 + 255) / 256, 256, 0, stream>>>(
        out, scale2, shift2, N * F_H / 4);
}

// Round 7
// 622.073 us; speedup vs baseline: 1.0612x; 1.0612x over previous
//
#include <hip/hip_runtime.h>

#define N_NODES 200000
#define N_EDGES 1200000
#define F_IN    64
#define F_H     128
#define BN_EPS  1e-5f

typedef short bf16x8 __attribute__((ext_vector_type(8)));   // 8 bf16 in 4 VGPRs
typedef float f32x4  __attribute__((ext_vector_type(4)));
typedef unsigned short us4 __attribute__((ext_vector_type(4)));

__device__ __forceinline__ unsigned short f2bf(float f) {
    union { float f; unsigned u; } v; v.f = f;
    unsigned r = (v.u + 0x7FFFu + ((v.u >> 16) & 1u)) >> 16;  // RNE
    return (unsigned short)r;
}
__device__ __forceinline__ float bf2f(unsigned short b) {
    union { unsigned u; float f; } v; v.u = ((unsigned)b) << 16;
    return v.f;
}

// ---------------------------------------------------------------------------
// Weight pack into bf16 MFMA B-fragment order for mfma_f32_16x16x32_bf16.
// ---------------------------------------------------------------------------
__global__ void pack_weights_kernel(const float* __restrict__ W,
                                    const float* __restrict__ kscale,
                                    short* __restrict__ P, int KT)
{
    int t = blockIdx.x * 256 + threadIdx.x;            // over 8*KT*64
    if (t >= 8 * KT * 64) return;
    int lane = t & 63;
    int kt   = (t >> 6) % KT;
    int nt   = t / (64 * KT);
    int k0   = kt * 32 + (lane >> 4) * 8;
    int n    = nt * 16 + (lane & 15);
#pragma unroll
    for (int j = 0; j < 8; ++j) {
        float w = W[(size_t)(k0 + j) * 128 + n];
        if (kscale) w *= kscale[k0 + j];
        P[(size_t)t * 8 + j] = (short)f2bf(w);
    }
}

// ---------------------------------------------------------------------------
// CSR build: histogram -> 2-level exclusive scan -> cursor fill
// ---------------------------------------------------------------------------
__global__ __launch_bounds__(256) void hist_kernel(const int* __restrict__ ei,
                                                   int* __restrict__ deg, int E)
{
    int e = blockIdx.x * 256 + threadIdx.x;
    if (e < E) atomicAdd(&deg[ei[E + e]], 1);
}

__global__ __launch_bounds__(256) void scan1_kernel(const int* __restrict__ deg,
        int* __restrict__ part, int* __restrict__ bsum, int n)
{
    __shared__ int s[256];
    int t = threadIdx.x;
    int base = blockIdx.x * 1024 + t * 4;
    int v[4];
#pragma unroll
    for (int j = 0; j < 4; ++j) v[j] = (base + j < n) ? deg[base + j] : 0;
    int tsum = v[0] + v[1] + v[2] + v[3];
    s[t] = tsum;
    __syncthreads();
    for (int off = 1; off < 256; off <<= 1) {
        int xv = (t >= off) ? s[t - off] : 0;
        __syncthreads();
        s[t] += xv;
        __syncthreads();
    }
    int excl = s[t] - tsum;
#pragma unroll
    for (int j = 0; j < 4; ++j) {
        if (base + j < n) part[base + j] = excl;
        excl += v[j];
    }
    if (t == 255) bsum[blockIdx.x] = s[255];
}

__global__ void scan2_kernel(int* __restrict__ bsum, int nb)
{
    __shared__ int s[256];
    int t = threadIdx.x;
    int v = (t < nb) ? bsum[t] : 0;
    s[t] = v;
    __syncthreads();
    for (int off = 1; off < 256; off <<= 1) {
        int xv = (t >= off) ? s[t - off] : 0;
        __syncthreads();
        s[t] += xv;
        __syncthreads();
    }
    if (t < nb) bsum[t] = s[t] - v;   // exclusive
}

__global__ __launch_bounds__(256) void scan3_kernel(
    const int* __restrict__ part, const int* __restrict__ bsum,
    const int* __restrict__ deg, int* __restrict__ rowptr,
    int* __restrict__ cursor, float* __restrict__ degf, int n, int E)
{
    int i = blockIdx.x * 256 + threadIdx.x;
    if (i == 0) rowptr[n] = E;
    if (i >= n) return;
    int r = part[i] + bsum[i >> 10];
    rowptr[i] = r;
    cursor[i] = r;
    degf[i]   = (float)deg[i];
}

__global__ __launch_bounds__(256) void fill_kernel(const int* __restrict__ ei,
        int* __restrict__ cursor, int* __restrict__ ssrc, int E)
{
    int e = blockIdx.x * 256 + threadIdx.x;
    if (e >= E) return;
    int d = ei[E + e];
    int pos = atomicAdd(&cursor[d], 1);
    ssrc[pos] = ei[e];
}

// ---------------------------------------------------------------------------
// Gather layer 1: aggb[row,0:64] = bf16( sum_src x[src,:] ).
// 4 rows/wave; neighbors batched x4 with next-batch index prefetch:
// 4 idx + 4 feature loads in flight per chain -> ~16-32 outstanding per wave.
// Out-of-range slots clamp to a safe address and are masked by a 0/1 flag.
// ---------------------------------------------------------------------------
__global__ __launch_bounds__(256) void gather1_kernel(
    const float* __restrict__ x, const int* __restrict__ rowptr,
    const int* __restrict__ ssrc, unsigned short* __restrict__ aggb)
{
    const int tid  = threadIdx.x;
    const int wv   = tid >> 6;
    const int lane = tid & 63;
    const int sub  = lane >> 4;
    const int li   = lane & 15;
    const int row  = blockIdx.x * 16 + wv * 4 + sub;

    const int b = rowptr[row], e = rowptr[row + 1];
    float4 acc = {0.f, 0.f, 0.f, 0.f};
    int s0 = row, s1 = row, s2 = row, s3 = row;
    if (b + 0 < e) s0 = ssrc[b + 0];
    if (b + 1 < e) s1 = ssrc[b + 1];
    if (b + 2 < e) s2 = ssrc[b + 2];
    if (b + 3 < e) s3 = ssrc[b + 3];
    for (int j = b; j < e; j += 4) {
        int n0 = row, n1 = row, n2 = row, n3 = row;
        int jn = j + 4;
        if (jn + 0 < e) n0 = ssrc[jn + 0];
        if (jn + 1 < e) n1 = ssrc[jn + 1];
        if (jn + 2 < e) n2 = ssrc[jn + 2];
        if (jn + 3 < e) n3 = ssrc[jn + 3];
        float4 v0 = ((const float4*)(x + (size_t)s0 * F_IN))[li];
        float4 v1 = ((const float4*)(x + (size_t)s1 * F_IN))[li];
        float4 v2 = ((const float4*)(x + (size_t)s2 * F_IN))[li];
        float4 v3 = ((const float4*)(x + (size_t)s3 * F_IN))[li];
        float w0 = (j + 0 < e) ? 1.f : 0.f;
        float w1 = (j + 1 < e) ? 1.f : 0.f;
        float w2 = (j + 2 < e) ? 1.f : 0.f;
        float w3 = (j + 3 < e) ? 1.f : 0.f;
        acc.x = fmaf(v0.x, w0, acc.x); acc.y = fmaf(v0.y, w0, acc.y);
        acc.z = fmaf(v0.z, w0, acc.z); acc.w = fmaf(v0.w, w0, acc.w);
        acc.x = fmaf(v1.x, w1, acc.x); acc.y = fmaf(v1.y, w1, acc.y);
        acc.z = fmaf(v1.z, w1, acc.z); acc.w = fmaf(v1.w, w1, acc.w);
        acc.x = fmaf(v2.x, w2, acc.x); acc.y = fmaf(v2.y, w2, acc.y);
        acc.z = fmaf(v2.z, w2, acc.z); acc.w = fmaf(v2.w, w2, acc.w);
        acc.x = fmaf(v3.x, w3, acc.x); acc.y = fmaf(v3.y, w3, acc.y);
        acc.z = fmaf(v3.z, w3, acc.z); acc.w = fmaf(v3.w, w3, acc.w);
        s0 = n0; s1 = n1; s2 = n2; s3 = n3;
    }
    us4 o;
    o.x = f2bf(acc.x); o.y = f2bf(acc.y); o.z = f2bf(acc.z); o.w = f2bf(acc.w);
    *(us4*)(aggb + (size_t)row * F_IN + li * 4) = o;
}

// ---------------------------------------------------------------------------
// Gather layer 2: aggb[row,0:128] = bf16( sum_src t1[src,:] ), same batching.
// ---------------------------------------------------------------------------
__global__ __launch_bounds__(256) void gather2_kernel(
    const unsigned short* __restrict__ t1, const int* __restrict__ rowptr,
    const int* __restrict__ ssrc, unsigned short* __restrict__ aggb)
{
    const int tid  = threadIdx.x;
    const int wv   = tid >> 6;
    const int lane = tid & 63;
    const int sub  = lane >> 4;
    const int li   = lane & 15;
    const int row  = blockIdx.x * 16 + wv * 4 + sub;

    const int b = rowptr[row], e = rowptr[row + 1];
    float acc[8] = {};
    int s0 = row, s1 = row, s2 = row, s3 = row;
    if (b + 0 < e) s0 = ssrc[b + 0];
    if (b + 1 < e) s1 = ssrc[b + 1];
    if (b + 2 < e) s2 = ssrc[b + 2];
    if (b + 3 < e) s3 = ssrc[b + 3];
    for (int j = b; j < e; j += 4) {
        int n0 = row, n1 = row, n2 = row, n3 = row;
        int jn = j + 4;
        if (jn + 0 < e) n0 = ssrc[jn + 0];
        if (jn + 1 < e) n1 = ssrc[jn + 1];
        if (jn + 2 < e) n2 = ssrc[jn + 2];
        if (jn + 3 < e) n3 = ssrc[jn + 3];
        bf16x8 v0 = *(const bf16x8*)(t1 + (size_t)s0 * F_H + li * 8);
        bf16x8 v1 = *(const bf16x8*)(t1 + (size_t)s1 * F_H + li * 8);
        bf16x8 v2 = *(const bf16x8*)(t1 + (size_t)s2 * F_H + li * 8);
        bf16x8 v3 = *(const bf16x8*)(t1 + (size_t)s3 * F_H + li * 8);
        float w0 = (j + 0 < e) ? 1.f : 0.f;
        float w1 = (j + 1 < e) ? 1.f : 0.f;
        float w2 = (j + 2 < e) ? 1.f : 0.f;
        float w3 = (j + 3 < e) ? 1.f : 0.f;
#pragma unroll
        for (int k = 0; k < 8; ++k) {
            acc[k] = fmaf(bf2f((unsigned short)v0[k]), w0, acc[k]);
            acc[k] = fmaf(bf2f((unsigned short)v1[k]), w1, acc[k]);
            acc[k] = fmaf(bf2f((unsigned short)v2[k]), w2, acc[k]);
            acc[k] = fmaf(bf2f((unsigned short)v3[k]), w3, acc[k]);
        }
        s0 = n0; s1 = n1; s2 = n2; s3 = n3;
    }
    bf16x8 o;
#pragma unroll
    for (int k = 0; k < 8; ++k) o[k] = (short)f2bf(acc[k]);
    *(bf16x8*)(aggb + (size_t)row * F_H + li * 8) = o;
}

// ---------------------------------------------------------------------------
// MFMA GEMM: 32 rows/wave (2 A-subtiles), 128 rows/block, flat grid 1563.
// acc = 2x8 f32x4 = 64 VGPR, leaving registers for a depth-2 software
// pipeline over kt: kt+1's A/X loads issue before kt's MFMAs (the load
// roundtrip overlaps compute; R4-R6 showed the kt chain was latency-
// serialized). Weights read from global (L2-resident, fragment order).
// Stats -> LDS reduce -> 128 atomics per block into 4 replicas.
// ---------------------------------------------------------------------------
template<int K, bool L2>
__global__ __launch_bounds__(256, 2) void gemm_mfma_kernel(
    const unsigned short* __restrict__ Ab,
    const float* __restrict__ Xf,
    const unsigned short* __restrict__ Xb,
    const bf16x8* __restrict__ Wlp, const bf16x8* __restrict__ Wrp,
    const float* __restrict__ bias,
    const float* __restrict__ c2, const float* __restrict__ degf,
    float* __restrict__ outF, unsigned short* __restrict__ outB,
    float* __restrict__ gsum, float* __restrict__ gsq)
{
    constexpr int KT = K / 32;
    __shared__ float sS[128];
    __shared__ float sQ[128];

    const int tid  = threadIdx.x;
    const int lane = tid & 63;
    const int wv   = tid >> 6;
    const int m    = lane & 15;
    const int quad = lane >> 4;
    const int rowbase = blockIdx.x * 128 + wv * 32;

    if (tid < 128) { sS[tid] = 0.f; sQ[tid] = 0.f; }

    // clamped row addresses for the 2 subtiles
    int rc[2];
#pragma unroll
    for (int st = 0; st < 2; ++st) {
        int r = rowbase + st * 16 + m;
        rc[st] = r < N_NODES ? r : N_NODES - 1;
    }

    // per-nt epilogue constants (col = nt*16 + m)
    float bcol[8], ccol[8];
#pragma unroll
    for (int nt = 0; nt < 8; ++nt) {
        bcol[nt] = bias[nt * 16 + m];
        if constexpr (L2) ccol[nt] = c2[nt * 16 + m];
    }

    f32x4 acc[2][8] = {};

    // ---- depth-2 pipelined kt loop ----
    auto load_kt = [&](int kt, bf16x8 af[2], bf16x8 xf[2]) {
        const int k0 = kt * 32 + quad * 8;
#pragma unroll
        for (int st = 0; st < 2; ++st) {
            af[st] = *(const bf16x8*)(Ab + (size_t)rc[st] * K + k0);
            if constexpr (L2) {
                xf[st] = *(const bf16x8*)(Xb + (size_t)rc[st] * K + k0);
            } else {
                const float4* xp = (const float4*)(Xf + (size_t)rc[st] * K + k0);
                float4 x0 = xp[0], x1 = xp[1];
                xf[st][0] = (short)f2bf(x0.x); xf[st][1] = (short)f2bf(x0.y);
                xf[st][2] = (short)f2bf(x0.z); xf[st][3] = (short)f2bf(x0.w);
                xf[st][4] = (short)f2bf(x1.x); xf[st][5] = (short)f2bf(x1.y);
                xf[st][6] = (short)f2bf(x1.z); xf[st][7] = (short)f2bf(x1.w);
            }
        }
    };

    bf16x8 aCur[2], xCur[2];
    load_kt(0, aCur, xCur);
#pragma unroll
    for (int kt = 0; kt < KT; ++kt) {
        bf16x8 aNxt[2], xNxt[2];
        if (kt + 1 < KT) load_kt(kt + 1, aNxt, xNxt);
#pragma unroll
        for (int nt = 0; nt < 8; ++nt) {
            bf16x8 wl = Wlp[(nt * KT + kt) * 64 + lane];
#pragma unroll
            for (int st = 0; st < 2; ++st)
                acc[st][nt] = __builtin_amdgcn_mfma_f32_16x16x32_bf16(
                    aCur[st], wl, acc[st][nt], 0, 0, 0);
            bf16x8 wr = Wrp[(nt * KT + kt) * 64 + lane];
#pragma unroll
            for (int st = 0; st < 2; ++st)
                acc[st][nt] = __builtin_amdgcn_mfma_f32_16x16x32_bf16(
                    xCur[st], wr, acc[st][nt], 0, 0, 0);
        }
#pragma unroll
        for (int st = 0; st < 2; ++st) { aCur[st] = aNxt[st]; xCur[st] = xNxt[st]; }
    }

    __syncthreads();   // sS/sQ init done

    // ---- epilogue: C/D layout col = lane&15, row = quad*4 + reg ----
    float stS[8] = {}, stQ[8] = {};
#pragma unroll
    for (int st = 0; st < 2; ++st) {
        const int orow = rowbase + st * 16 + quad * 4;
        float dg[4];
        if constexpr (L2) {
#pragma unroll
            for (int r = 0; r < 4; ++r) {
                int rr = orow + r;
                dg[r] = (rr < N_NODES) ? degf[rr] : 0.f;
            }
        }
#pragma unroll
        for (int nt = 0; nt < 8; ++nt) {
            int col = nt * 16 + m;
#pragma unroll
            for (int r = 0; r < 4; ++r) {
                int rr = orow + r;
                if (rr < N_NODES) {
                    float base = L2 ? fmaf(dg[r], ccol[nt], bcol[nt]) : bcol[nt];
                    float v = fmaxf(acc[st][nt][r] + base, 0.f);
                    if constexpr (L2) outF[(size_t)rr * 128 + col] = v;
                    else              outB[(size_t)rr * 128 + col] = f2bf(v);
                    stS[nt] += v;
                    stQ[nt] = fmaf(v, v, stQ[nt]);
                }
            }
        }
    }

    // ---- stats reduce: registers -> LDS -> global replica (blockIdx&3) ----
#pragma unroll
    for (int nt = 0; nt < 8; ++nt) {
        atomicAdd(&sS[nt * 16 + m], stS[nt]);
        atomicAdd(&sQ[nt * 16 + m], stQ[nt]);
    }
    __syncthreads();
    const int rep = (blockIdx.x & 3) * 128;
    if (tid < 128) {
        atomicAdd(&gsum[rep + tid], sS[tid]);
        atomicAdd(&gsq[rep + tid],  sQ[tid]);
    }
}

// ---------------------------------------------------------------------------
// BN finalize: per-feature scale/shift (sums the 4 stats replicas).
// ---------------------------------------------------------------------------
__global__ void bn_finalize_kernel(
    const float* __restrict__ gsum, const float* __restrict__ gsq,
    const float* __restrict__ g, const float* __restrict__ be,
    float* __restrict__ scale, float* __restrict__ shift, float invN)
{
    int c = threadIdx.x;  // 128
    float s = gsum[c] + gsum[128 + c] + gsum[256 + c] + gsum[384 + c];
    float q = gsq[c]  + gsq[128 + c]  + gsq[256 + c]  + gsq[384 + c];
    float mean = s * invN;
    float var  = fmaxf(q * invN - mean * mean, 0.f);
    float sc   = g[c] * rsqrtf(var + BN_EPS);
    scale[c] = sc;
    shift[c] = be[c] - mean * sc;
}

// BN1 fold constants: c2 = shift1@W2l ; crb = shift1@W2r + b2
__global__ void bn_fold_kernel(
    const float* __restrict__ shift1, const float* __restrict__ W2l,
    const float* __restrict__ W2r, const float* __restrict__ b2,
    float* __restrict__ c2, float* __restrict__ crb)
{
    int col = threadIdx.x;  // 128
    float a = 0.f, r = 0.f;
    for (int k = 0; k < 128; ++k) {
        float s = shift1[k];
        a = fmaf(s, W2l[(size_t)k * 128 + col], a);
        r = fmaf(s, W2r[(size_t)k * 128 + col], r);
    }
    c2[col]  = a;
    crb[col] = r + b2[col];
}

// ---------------------------------------------------------------------------
// Final BN apply + ReLU (in place on d_out).
// ---------------------------------------------------------------------------
__global__ __launch_bounds__(256) void bn_apply_relu_kernel(
    float* __restrict__ h, const float* __restrict__ scale,
    const float* __restrict__ shift, int n4)
{
    int i = blockIdx.x * 256 + threadIdx.x;
    if (i >= n4) return;
    int cb = i & 31;
    float4 v  = ((float4*)h)[i];
    float4 sc = ((const float4*)scale)[cb];
    float4 sh = ((const float4*)shift)[cb];
    v.x = fmaxf(fmaf(v.x, sc.x, sh.x), 0.f);
    v.y = fmaxf(fmaf(v.y, sc.y, sh.y), 0.f);
    v.z = fmaxf(fmaf(v.z, sc.z, sh.z), 0.f);
    v.w = fmaxf(fmaf(v.w, sc.w, sh.w), 0.f);
    ((float4*)h)[i] = v;
}

extern "C" void kernel_launch(void* const* d_in, const int* in_sizes, int n_in,
                              void* d_out, int out_size, void* d_ws, size_t ws_size,
                              hipStream_t stream) {
    const float* x   = (const float*)d_in[0];
    const int*   ei  = (const int*)d_in[1];
    const float* W1l = (const float*)d_in[2];
    const float* b1  = (const float*)d_in[3];
    const float* W1r = (const float*)d_in[4];
    const float* g1  = (const float*)d_in[5];
    const float* be1 = (const float*)d_in[6];
    const float* W2l = (const float*)d_in[7];
    const float* b2  = (const float*)d_in[8];
    const float* W2r = (const float*)d_in[9];
    const float* g2  = (const float*)d_in[10];
    const float* be2 = (const float*)d_in[11];
    float* out = (float*)d_out;

    const int N = N_NODES, E = N_EDGES;
    const int NB1 = (N + 1023) / 1024;          // 196 scan blocks
    const int nT  = (N + 127) / 128;            // 1563 gemm blocks

    // Workspace layout (float units):
    float* ws     = (float*)d_ws;
    float* gsum1  = ws;          float* gsq1   = ws + 512;    // 4 replicas x 128
    float* gsum2  = ws + 1024;   float* gsq2   = ws + 1536;
    float* scale1 = ws + 2048;   float* shift1 = ws + 2176;
    float* scale2 = ws + 2304;   float* shift2 = ws + 2432;
    float* c2v    = ws + 2560;   float* crb    = ws + 2688;
    short* W1lp = (short*)(ws + 3072);                        // 4096 f
    short* W1rp = (short*)(ws + 3072 + 4096);                 // 4096 f
    short* W2lp = (short*)(ws + 3072 + 8192);                 // 8192 f
    short* W2rp = (short*)(ws + 3072 + 16384);                // 8192 f
    int*   deg    = (int*)(ws + 27648);                       // N
    int*   part   = deg + N;                                  // N
    int*   bsum   = part + N;                                 // 1024
    int*   rowptr = bsum + 1024;                              // N+1
    int*   cursor = rowptr + (N + 1024);                      // N (padded)
    float* degf   = (float*)(cursor + N);                     // N
    int*   ssrc   = (int*)(degf + N);                         // E
    unsigned short* t1   = (unsigned short*)(ssrc + E);       // N*128 bf16
    unsigned short* aggb = t1 + (size_t)N * F_H;              // N*128 bf16

    // ---- Graph build + layer-1 weight pack ----
    hipMemsetAsync(ws, 0, 2048 * sizeof(float), stream);      // stats replicas
    hipMemsetAsync(deg, 0, (size_t)N * sizeof(int), stream);
    pack_weights_kernel<<<4, 256, 0, stream>>>(W1l, nullptr, W1lp, 2);
    pack_weights_kernel<<<4, 256, 0, stream>>>(W1r, nullptr, W1rp, 2);
    hist_kernel<<<(E + 255) / 256, 256, 0, stream>>>(ei, deg, E);
    scan1_kernel<<<NB1, 256, 0, stream>>>(deg, part, bsum, N);
    scan2_kernel<<<1, 256, 0, stream>>>(bsum, NB1);
    scan3_kernel<<<(N + 255) / 256, 256, 0, stream>>>(part, bsum, deg, rowptr,
                                                      cursor, degf, N, E);
    fill_kernel<<<(E + 255) / 256, 256, 0, stream>>>(ei, cursor, ssrc, E);

    // ---- Layer 1 ----
    gather1_kernel<<<N / 16, 256, 0, stream>>>(x, rowptr, ssrc, aggb);
    gemm_mfma_kernel<F_IN, false><<<nT, 256, 0, stream>>>(
        aggb, x, nullptr, (const bf16x8*)W1lp, (const bf16x8*)W1rp, b1,
        nullptr, nullptr, nullptr, t1, gsum1, gsq1);
    bn_finalize_kernel<<<1, 128, 0, stream>>>(gsum1, gsq1, g1, be1,
                                              scale1, shift1, 1.f / N);

    // ---- Layer 2 (BN1 folded: scale1 into weights, shift1 into c2/crb) ----
    pack_weights_kernel<<<8, 256, 0, stream>>>(W2l, scale1, W2lp, 4);
    pack_weights_kernel<<<8, 256, 0, stream>>>(W2r, scale1, W2rp, 4);
    bn_fold_kernel<<<1, 128, 0, stream>>>(shift1, W2l, W2r, b2, c2v, crb);
    gather2_kernel<<<N / 16, 256, 0, stream>>>(t1, rowptr, ssrc, aggb);
    gemm_mfma_kernel<F_H, true><<<nT, 256, 0, stream>>>(
        aggb, nullptr, t1, (const bf16x8*)W2lp, (const bf16x8*)W2rp, crb,
        c2v, degf, out, nullptr, gsum2, gsq2);
    bn_finalize_kernel<<<1, 128, 0, stream>>>(gsum2, gsq2, g2, be2,
                                              scale2, shift2, 1.f / N);
    bn_apply_relu_kernel<<<(N * F_H / 4 + 255) / 256, 256, 0, stream>>>(
        out, scale2, shift2, N * F_H / 4);
}

// Round 8
// 607.054 us; speedup vs baseline: 1.0874x; 1.0247x over previous
//
#include <hip/hip_runtime.h>

#define N_NODES 200000
#define N_EDGES 1200000
#define F_IN    64
#define F_H     128
#define BN_EPS  1e-5f

typedef short bf16x8 __attribute__((ext_vector_type(8)));   // 8 bf16 in 4 VGPRs
typedef float f32x4  __attribute__((ext_vector_type(4)));
typedef unsigned short us4 __attribute__((ext_vector_type(4)));

__device__ __forceinline__ unsigned short f2bf(float f) {
    union { float f; unsigned u; } v; v.f = f;
    unsigned r = (v.u + 0x7FFFu + ((v.u >> 16) & 1u)) >> 16;  // RNE
    return (unsigned short)r;
}
__device__ __forceinline__ float bf2f(unsigned short b) {
    union { unsigned u; float f; } v; v.u = ((unsigned)b) << 16;
    return v.f;
}

// ---------------------------------------------------------------------------
// Weight pack into bf16 MFMA B-fragment order for mfma_f32_16x16x32_bf16.
// ---------------------------------------------------------------------------
__global__ void pack_weights_kernel(const float* __restrict__ W,
                                    const float* __restrict__ kscale,
                                    short* __restrict__ P, int KT)
{
    int t = blockIdx.x * 256 + threadIdx.x;            // over 8*KT*64
    if (t >= 8 * KT * 64) return;
    int lane = t & 63;
    int kt   = (t >> 6) % KT;
    int nt   = t / (64 * KT);
    int k0   = kt * 32 + (lane >> 4) * 8;
    int n    = nt * 16 + (lane & 15);
#pragma unroll
    for (int j = 0; j < 8; ++j) {
        float w = W[(size_t)(k0 + j) * 128 + n];
        if (kscale) w *= kscale[k0 + j];
        P[(size_t)t * 8 + j] = (short)f2bf(w);
    }
}

// ---------------------------------------------------------------------------
// CSR build: histogram -> 2-level exclusive scan -> cursor fill
// ---------------------------------------------------------------------------
__global__ __launch_bounds__(256) void hist_kernel(const int* __restrict__ ei,
                                                   int* __restrict__ deg, int E)
{
    int e = blockIdx.x * 256 + threadIdx.x;
    if (e < E) atomicAdd(&deg[ei[E + e]], 1);
}

__global__ __launch_bounds__(256) void scan1_kernel(const int* __restrict__ deg,
        int* __restrict__ part, int* __restrict__ bsum, int n)
{
    __shared__ int s[256];
    int t = threadIdx.x;
    int base = blockIdx.x * 1024 + t * 4;
    int v[4];
#pragma unroll
    for (int j = 0; j < 4; ++j) v[j] = (base + j < n) ? deg[base + j] : 0;
    int tsum = v[0] + v[1] + v[2] + v[3];
    s[t] = tsum;
    __syncthreads();
    for (int off = 1; off < 256; off <<= 1) {
        int xv = (t >= off) ? s[t - off] : 0;
        __syncthreads();
        s[t] += xv;
        __syncthreads();
    }
    int excl = s[t] - tsum;
#pragma unroll
    for (int j = 0; j < 4; ++j) {
        if (base + j < n) part[base + j] = excl;
        excl += v[j];
    }
    if (t == 255) bsum[blockIdx.x] = s[255];
}

__global__ void scan2_kernel(int* __restrict__ bsum, int nb)
{
    __shared__ int s[256];
    int t = threadIdx.x;
    int v = (t < nb) ? bsum[t] : 0;
    s[t] = v;
    __syncthreads();
    for (int off = 1; off < 256; off <<= 1) {
        int xv = (t >= off) ? s[t - off] : 0;
        __syncthreads();
        s[t] += xv;
        __syncthreads();
    }
    if (t < nb) bsum[t] = s[t] - v;   // exclusive
}

__global__ __launch_bounds__(256) void scan3_kernel(
    const int* __restrict__ part, const int* __restrict__ bsum,
    const int* __restrict__ deg, int* __restrict__ rowptr,
    int* __restrict__ cursor, float* __restrict__ degf, int n, int E)
{
    int i = blockIdx.x * 256 + threadIdx.x;
    if (i == 0) rowptr[n] = E;
    if (i >= n) return;
    int r = part[i] + bsum[i >> 10];
    rowptr[i] = r;
    cursor[i] = r;
    degf[i]   = (float)deg[i];
}

__global__ __launch_bounds__(256) void fill_kernel(const int* __restrict__ ei,
        int* __restrict__ cursor, int* __restrict__ ssrc, int E)
{
    int e = blockIdx.x * 256 + threadIdx.x;
    if (e >= E) return;
    int d = ei[E + e];
    int pos = atomicAdd(&cursor[d], 1);
    ssrc[pos] = ei[e];
}

// ---------------------------------------------------------------------------
// Gather layer 1: aggb[row,0:64] = bf16( sum_src x[src,:] ).
// 4 rows/wave; neighbors batched x8 (8 feature loads + 8 index prefetches in
// flight per iteration; masked slots clamp to `row` and multiply by 0).
// ---------------------------------------------------------------------------
__global__ __launch_bounds__(256) void gather1_kernel(
    const float* __restrict__ x, const int* __restrict__ rowptr,
    const int* __restrict__ ssrc, unsigned short* __restrict__ aggb)
{
    const int tid  = threadIdx.x;
    const int wv   = tid >> 6;
    const int lane = tid & 63;
    const int sub  = lane >> 4;
    const int li   = lane & 15;
    const int row  = blockIdx.x * 16 + wv * 4 + sub;

    const int b = rowptr[row], e = rowptr[row + 1];
    float4 acc = {0.f, 0.f, 0.f, 0.f};
    int s[8];
#pragma unroll
    for (int q = 0; q < 8; ++q) s[q] = (b + q < e) ? ssrc[b + q] : row;
    for (int j = b; j < e; j += 8) {
        int nn[8];
        const int jn = j + 8;
#pragma unroll
        for (int q = 0; q < 8; ++q) nn[q] = (jn + q < e) ? ssrc[jn + q] : row;
        float4 v[8];
#pragma unroll
        for (int q = 0; q < 8; ++q)
            v[q] = ((const float4*)(x + (size_t)s[q] * F_IN))[li];
#pragma unroll
        for (int q = 0; q < 8; ++q) {
            float w = (j + q < e) ? 1.f : 0.f;
            acc.x = fmaf(v[q].x, w, acc.x);
            acc.y = fmaf(v[q].y, w, acc.y);
            acc.z = fmaf(v[q].z, w, acc.z);
            acc.w = fmaf(v[q].w, w, acc.w);
        }
#pragma unroll
        for (int q = 0; q < 8; ++q) s[q] = nn[q];
    }
    us4 o;
    o.x = f2bf(acc.x); o.y = f2bf(acc.y); o.z = f2bf(acc.z); o.w = f2bf(acc.w);
    *(us4*)(aggb + (size_t)row * F_IN + li * 4) = o;
}

// ---------------------------------------------------------------------------
// Gather layer 2: aggb[row,0:128] = bf16( sum_src t1[src,:] ), batch x8.
// ---------------------------------------------------------------------------
__global__ __launch_bounds__(256) void gather2_kernel(
    const unsigned short* __restrict__ t1, const int* __restrict__ rowptr,
    const int* __restrict__ ssrc, unsigned short* __restrict__ aggb)
{
    const int tid  = threadIdx.x;
    const int wv   = tid >> 6;
    const int lane = tid & 63;
    const int sub  = lane >> 4;
    const int li   = lane & 15;
    const int row  = blockIdx.x * 16 + wv * 4 + sub;

    const int b = rowptr[row], e = rowptr[row + 1];
    float acc[8] = {};
    int s[8];
#pragma unroll
    for (int q = 0; q < 8; ++q) s[q] = (b + q < e) ? ssrc[b + q] : row;
    for (int j = b; j < e; j += 8) {
        int nn[8];
        const int jn = j + 8;
#pragma unroll
        for (int q = 0; q < 8; ++q) nn[q] = (jn + q < e) ? ssrc[jn + q] : row;
        bf16x8 v[8];
#pragma unroll
        for (int q = 0; q < 8; ++q)
            v[q] = *(const bf16x8*)(t1 + (size_t)s[q] * F_H + li * 8);
#pragma unroll
        for (int q = 0; q < 8; ++q) {
            float w = (j + q < e) ? 1.f : 0.f;
#pragma unroll
            for (int k = 0; k < 8; ++k)
                acc[k] = fmaf(bf2f((unsigned short)v[q][k]), w, acc[k]);
        }
#pragma unroll
        for (int q = 0; q < 8; ++q) s[q] = nn[q];
    }
    bf16x8 o;
#pragma unroll
    for (int k = 0; k < 8; ++k) o[k] = (short)f2bf(acc[k]);
    *(bf16x8*)(aggb + (size_t)row * F_H + li * 8) = o;
}

// ---------------------------------------------------------------------------
// MFMA GEMM: 32 rows/wave (2 subtiles), 128 rows/block, flat grid 1563.
// ALL A/X row-slices for the wave are loaded up front (K=128: 16 x 1KB loads
// = 16 KB/wave in flight; Little's law — R4-R7 structures all starved the
// memory system at ~4 KB/wave). The kt loop is then pure weight-load
// (L1/L2-hit) + MFMA with no HBM dependency.
// Stats -> LDS reduce -> 128 atomics per block into 4 replicas.
// ---------------------------------------------------------------------------
template<int K, bool L2>
__global__ __launch_bounds__(256, 2) void gemm_mfma_kernel(
    const unsigned short* __restrict__ Ab,
    const float* __restrict__ Xf,
    const unsigned short* __restrict__ Xb,
    const bf16x8* __restrict__ Wlp, const bf16x8* __restrict__ Wrp,
    const float* __restrict__ bias,
    const float* __restrict__ c2, const float* __restrict__ degf,
    float* __restrict__ outF, unsigned short* __restrict__ outB,
    float* __restrict__ gsum, float* __restrict__ gsq)
{
    constexpr int KT = K / 32;
    __shared__ float sS[128];
    __shared__ float sQ[128];

    const int tid  = threadIdx.x;
    const int lane = tid & 63;
    const int wv   = tid >> 6;
    const int m    = lane & 15;
    const int quad = lane >> 4;
    const int rowbase = blockIdx.x * 128 + wv * 32;

    if (tid < 128) { sS[tid] = 0.f; sQ[tid] = 0.f; }

    int rc[2];
#pragma unroll
    for (int st = 0; st < 2; ++st) {
        int r = rowbase + st * 16 + m;
        rc[st] = r < N_NODES ? r : N_NODES - 1;
    }

    // ---- upfront load of the wave's full A and X row-slices ----
    bf16x8 aReg[2][KT], xReg[2][KT];
#pragma unroll
    for (int st = 0; st < 2; ++st) {
        const unsigned short* ap = Ab + (size_t)rc[st] * K + quad * 8;
#pragma unroll
        for (int kt = 0; kt < KT; ++kt)
            aReg[st][kt] = *(const bf16x8*)(ap + kt * 32);
    }
    if constexpr (L2) {
#pragma unroll
        for (int st = 0; st < 2; ++st) {
            const unsigned short* xp = Xb + (size_t)rc[st] * K + quad * 8;
#pragma unroll
            for (int kt = 0; kt < KT; ++kt)
                xReg[st][kt] = *(const bf16x8*)(xp + kt * 32);
        }
    } else {
        float4 xr[2][KT][2];
#pragma unroll
        for (int st = 0; st < 2; ++st) {
            const float* xp = Xf + (size_t)rc[st] * K + quad * 8;
#pragma unroll
            for (int kt = 0; kt < KT; ++kt) {
                xr[st][kt][0] = *(const float4*)(xp + kt * 32);
                xr[st][kt][1] = *(const float4*)(xp + kt * 32 + 4);
            }
        }
#pragma unroll
        for (int st = 0; st < 2; ++st)
#pragma unroll
            for (int kt = 0; kt < KT; ++kt) {
                xReg[st][kt][0] = (short)f2bf(xr[st][kt][0].x);
                xReg[st][kt][1] = (short)f2bf(xr[st][kt][0].y);
                xReg[st][kt][2] = (short)f2bf(xr[st][kt][0].z);
                xReg[st][kt][3] = (short)f2bf(xr[st][kt][0].w);
                xReg[st][kt][4] = (short)f2bf(xr[st][kt][1].x);
                xReg[st][kt][5] = (short)f2bf(xr[st][kt][1].y);
                xReg[st][kt][6] = (short)f2bf(xr[st][kt][1].z);
                xReg[st][kt][7] = (short)f2bf(xr[st][kt][1].w);
            }
    }

    // per-nt epilogue constants (col = nt*16 + m)
    float bcol[8], ccol[8];
#pragma unroll
    for (int nt = 0; nt < 8; ++nt) {
        bcol[nt] = bias[nt * 16 + m];
        if constexpr (L2) ccol[nt] = c2[nt * 16 + m];
    }

    f32x4 acc[2][8] = {};

    // ---- K loop: weight loads (L1/L2-hit) + MFMA only ----
#pragma unroll
    for (int kt = 0; kt < KT; ++kt) {
#pragma unroll
        for (int nt = 0; nt < 8; ++nt) {
            bf16x8 wl = Wlp[(nt * KT + kt) * 64 + lane];
#pragma unroll
            for (int st = 0; st < 2; ++st)
                acc[st][nt] = __builtin_amdgcn_mfma_f32_16x16x32_bf16(
                    aReg[st][kt], wl, acc[st][nt], 0, 0, 0);
            bf16x8 wr = Wrp[(nt * KT + kt) * 64 + lane];
#pragma unroll
            for (int st = 0; st < 2; ++st)
                acc[st][nt] = __builtin_amdgcn_mfma_f32_16x16x32_bf16(
                    xReg[st][kt], wr, acc[st][nt], 0, 0, 0);
        }
    }

    __syncthreads();   // sS/sQ init done

    // ---- epilogue: C/D layout col = lane&15, row = quad*4 + reg ----
    float stS[8] = {}, stQ[8] = {};
#pragma unroll
    for (int st = 0; st < 2; ++st) {
        const int orow = rowbase + st * 16 + quad * 4;
        float dg[4];
        if constexpr (L2) {
#pragma unroll
            for (int r = 0; r < 4; ++r) {
                int rr = orow + r;
                dg[r] = (rr < N_NODES) ? degf[rr] : 0.f;
            }
        }
#pragma unroll
        for (int nt = 0; nt < 8; ++nt) {
            int col = nt * 16 + m;
#pragma unroll
            for (int r = 0; r < 4; ++r) {
                int rr = orow + r;
                if (rr < N_NODES) {
                    float base = L2 ? fmaf(dg[r], ccol[nt], bcol[nt]) : bcol[nt];
                    float v = fmaxf(acc[st][nt][r] + base, 0.f);
                    if constexpr (L2) outF[(size_t)rr * 128 + col] = v;
                    else              outB[(size_t)rr * 128 + col] = f2bf(v);
                    stS[nt] += v;
                    stQ[nt] = fmaf(v, v, stQ[nt]);
                }
            }
        }
    }

    // ---- stats reduce: registers -> LDS -> global replica (blockIdx&3) ----
#pragma unroll
    for (int nt = 0; nt < 8; ++nt) {
        atomicAdd(&sS[nt * 16 + m], stS[nt]);
        atomicAdd(&sQ[nt * 16 + m], stQ[nt]);
    }
    __syncthreads();
    const int rep = (blockIdx.x & 3) * 128;
    if (tid < 128) {
        atomicAdd(&gsum[rep + tid], sS[tid]);
        atomicAdd(&gsq[rep + tid],  sQ[tid]);
    }
}

// ---------------------------------------------------------------------------
// BN finalize: per-feature scale/shift (sums the 4 stats replicas).
// ---------------------------------------------------------------------------
__global__ void bn_finalize_kernel(
    const float* __restrict__ gsum, const float* __restrict__ gsq,
    const float* __restrict__ g, const float* __restrict__ be,
    float* __restrict__ scale, float* __restrict__ shift, float invN)
{
    int c = threadIdx.x;  // 128
    float s = gsum[c] + gsum[128 + c] + gsum[256 + c] + gsum[384 + c];
    float q = gsq[c]  + gsq[128 + c]  + gsq[256 + c]  + gsq[384 + c];
    float mean = s * invN;
    float var  = fmaxf(q * invN - mean * mean, 0.f);
    float sc   = g[c] * rsqrtf(var + BN_EPS);
    scale[c] = sc;
    shift[c] = be[c] - mean * sc;
}

// BN1 fold constants: c2 = shift1@W2l ; crb = shift1@W2r + b2
__global__ void bn_fold_kernel(
    const float* __restrict__ shift1, const float* __restrict__ W2l,
    const float* __restrict__ W2r, const float* __restrict__ b2,
    float* __restrict__ c2, float* __restrict__ crb)
{
    int col = threadIdx.x;  // 128
    float a = 0.f, r = 0.f;
    for (int k = 0; k < 128; ++k) {
        float s = shift1[k];
        a = fmaf(s, W2l[(size_t)k * 128 + col], a);
        r = fmaf(s, W2r[(size_t)k * 128 + col], r);
    }
    c2[col]  = a;
    crb[col] = r + b2[col];
}

// ---------------------------------------------------------------------------
// Final BN apply + ReLU (in place on d_out).
// ---------------------------------------------------------------------------
__global__ __launch_bounds__(256) void bn_apply_relu_kernel(
    float* __restrict__ h, const float* __restrict__ scale,
    const float* __restrict__ shift, int n4)
{
    int i = blockIdx.x * 256 + threadIdx.x;
    if (i >= n4) return;
    int cb = i & 31;
    float4 v  = ((float4*)h)[i];
    float4 sc = ((const float4*)scale)[cb];
    float4 sh = ((const float4*)shift)[cb];
    v.x = fmaxf(fmaf(v.x, sc.x, sh.x), 0.f);
    v.y = fmaxf(fmaf(v.y, sc.y, sh.y), 0.f);
    v.z = fmaxf(fmaf(v.z, sc.z, sh.z), 0.f);
    v.w = fmaxf(fmaf(v.w, sc.w, sh.w), 0.f);
    ((float4*)h)[i] = v;
}

extern "C" void kernel_launch(void* const* d_in, const int* in_sizes, int n_in,
                              void* d_out, int out_size, void* d_ws, size_t ws_size,
                              hipStream_t stream) {
    const float* x   = (const float*)d_in[0];
    const int*   ei  = (const int*)d_in[1];
    const float* W1l = (const float*)d_in[2];
    const float* b1  = (const float*)d_in[3];
    const float* W1r = (const float*)d_in[4];
    const float* g1  = (const float*)d_in[5];
    const float* be1 = (const float*)d_in[6];
    const float* W2l = (const float*)d_in[7];
    const float* b2  = (const float*)d_in[8];
    const float* W2r = (const float*)d_in[9];
    const float* g2  = (const float*)d_in[10];
    const float* be2 = (const float*)d_in[11];
    float* out = (float*)d_out;

    const int N = N_NODES, E = N_EDGES;
    const int NB1 = (N + 1023) / 1024;          // 196 scan blocks
    const int nT  = (N + 127) / 128;            // 1563 gemm blocks

    // Workspace layout (float units):
    float* ws     = (float*)d_ws;
    float* gsum1  = ws;          float* gsq1   = ws + 512;    // 4 replicas x 128
    float* gsum2  = ws + 1024;   float* gsq2   = ws + 1536;
    float* scale1 = ws + 2048;   float* shift1 = ws + 2176;
    float* scale2 = ws + 2304;   float* shift2 = ws + 2432;
    float* c2v    = ws + 2560;   float* crb    = ws + 2688;
    short* W1lp = (short*)(ws + 3072);                        // 4096 f
    short* W1rp = (short*)(ws + 3072 + 4096);                 // 4096 f
    short* W2lp = (short*)(ws + 3072 + 8192);                 // 8192 f
    short* W2rp = (short*)(ws + 3072 + 16384);                // 8192 f
    int*   deg    = (int*)(ws + 27648);                       // N
    int*   part   = deg + N;                                  // N
    int*   bsum   = part + N;                                 // 1024
    int*   rowptr = bsum + 1024;                              // N+1
    int*   cursor = rowptr + (N + 1024);                      // N (padded)
    float* degf   = (float*)(cursor + N);                     // N
    int*   ssrc   = (int*)(degf + N);                         // E
    unsigned short* t1   = (unsigned short*)(ssrc + E);       // N*128 bf16
    unsigned short* aggb = t1 + (size_t)N * F_H;              // N*128 bf16

    // ---- Graph build + layer-1 weight pack ----
    hipMemsetAsync(ws, 0, 2048 * sizeof(float), stream);      // stats replicas
    hipMemsetAsync(deg, 0, (size_t)N * sizeof(int), stream);
    pack_weights_kernel<<<4, 256, 0, stream>>>(W1l, nullptr, W1lp, 2);
    pack_weights_kernel<<<4, 256, 0, stream>>>(W1r, nullptr, W1rp, 2);
    hist_kernel<<<(E + 255) / 256, 256, 0, stream>>>(ei, deg, E);
    scan1_kernel<<<NB1, 256, 0, stream>>>(deg, part, bsum, N);
    scan2_kernel<<<1, 256, 0, stream>>>(bsum, NB1);
    scan3_kernel<<<(N + 255) / 256, 256, 0, stream>>>(part, bsum, deg, rowptr,
                                                      cursor, degf, N, E);
    fill_kernel<<<(E + 255) / 256, 256, 0, stream>>>(ei, cursor, ssrc, E);

    // ---- Layer 1 ----
    gather1_kernel<<<N / 16, 256, 0, stream>>>(x, rowptr, ssrc, aggb);
    gemm_mfma_kernel<F_IN, false><<<nT, 256, 0, stream>>>(
        aggb, x, nullptr, (const bf16x8*)W1lp, (const bf16x8*)W1rp, b1,
        nullptr, nullptr, nullptr, t1, gsum1, gsq1);
    bn_finalize_kernel<<<1, 128, 0, stream>>>(gsum1, gsq1, g1, be1,
                                              scale1, shift1, 1.f / N);

    // ---- Layer 2 (BN1 folded: scale1 into weights, shift1 into c2/crb) ----
    pack_weights_kernel<<<8, 256, 0, stream>>>(W2l, scale1, W2lp, 4);
    pack_weights_kernel<<<8, 256, 0, stream>>>(W2r, scale1, W2rp, 4);
    bn_fold_kernel<<<1, 128, 0, stream>>>(shift1, W2l, W2r, b2, c2v, crb);
    gather2_kernel<<<N / 16, 256, 0, stream>>>(t1, rowptr, ssrc, aggb);
    gemm_mfma_kernel<F_H, true><<<nT, 256, 0, stream>>>(
        aggb, nullptr, t1, (const bf16x8*)W2lp, (const bf16x8*)W2rp, crb,
        c2v, degf, out, nullptr, gsum2, gsq2);
    bn_finalize_kernel<<<1, 128, 0, stream>>>(gsum2, gsq2, g2, be2,
                                              scale2, shift2, 1.f / N);
    bn_apply_relu_kernel<<<(N * F_H / 4 + 255) / 256, 256, 0, stream>>>(
        out, scale2, shift2, N * F_H / 4);
}